// Round 15
// baseline (422.283 us; speedup 1.0000x reference)
//
#include <hip/hip_runtime.h>

// Problem constants: B=2, S=2048, E=1024, H=16, DH=64. All fp32 in/out.
// Pipeline:
//   1) convert q,k,v,Wq,Wk,Wv,Wo fp32->bf16              (1 launch)
//   2) Q/K/V projections, fused bf16 NT-GEMM (z=3 grid)  (1 launch)
//      V-projection (z=2) writes directly in VT[b][h][d][s] layout
//      (transpose fused into epilogue; r=0..3 = 4 consecutive s -> 8B store).
//   3) fused attention with cross-head logit mixing      (1 launch)
//      v9-verbatim attention: 241us floor of this decomposition (13
//      structural variants: time = per-wave work x ~10 latency factor).
//   4) out = O @ Wo^T + bo, fp32 to d_out                (1 launch)
// v15: gemm_bt moved to DOUBLE-BUFFERED global_load_lds staging (T3
// "minimum 2-phase"): per K-step issue stage(buf^1, kt+32) FIRST, then
// ds_read+16 MFMA from buf, then ONE __syncthreads (vmcnt+lgkm drain =
// exactly the needed hazards: next-buf loads landed, cur-buf reads
// retired). v13's glds attempt lost because it staged into the SAME
// buffer it was about to read -- zero compute cover before the drain.
// Dbuf gives ~230cy in-wave cover + 3 blocks/CU cross-block overlap,
// and deletes 4 ds_writes + 8 staging VGPRs per thread per step
// (m151: glds 874 vs reg-staged 646 TF at 128^2 tile).
// Workspace layout (56 MB total; Obuf overlays q_bf).

typedef __attribute__((ext_vector_type(8))) short bf16x8_t;   // 8 bf16 (4 VGPRs)
typedef __attribute__((ext_vector_type(4))) short bf16x4_t;   // 4 bf16 (2 VGPRs)
typedef __attribute__((ext_vector_type(4))) float f32x4_t;    // MFMA accumulator

__device__ inline unsigned short f2bf(float f) {
  unsigned u = __builtin_bit_cast(unsigned, f);
  u += 0x7fffu + ((u >> 16) & 1u);          // round-to-nearest-even
  return (unsigned short)(u >> 16);
}

// Direct global->LDS async copy, 16B per lane. LDS destination must be
// wave-uniform base + lane*16 (our t*16B staging layout satisfies this).
// Completion tracked by vmcnt; __syncthreads (vmcnt(0) drain) publishes.
#define GLDS16(gp, lp)                                                  \
  __builtin_amdgcn_global_load_lds(                                     \
      (const __attribute__((address_space(1))) unsigned int*)(gp),      \
      (__attribute__((address_space(3))) unsigned int*)(lp), 16, 0, 0)

struct ConvArgs {
  const float* src[7];
  unsigned short* dst[7];
  int n[7];
};

__global__ __launch_bounds__(256) void convert_f32_bf16(ConvArgs a) {
  const int which = blockIdx.y;
  const int i = (blockIdx.x * 256 + threadIdx.x) * 8;
  if (i >= a.n[which]) return;
  const float* s = a.src[which] + i;
  f32x4_t x0 = *(const f32x4_t*)(s);
  f32x4_t x1 = *(const f32x4_t*)(s + 4);
  bf16x8_t o;
#pragma unroll
  for (int j = 0; j < 4; j++) o[j] = (short)f2bf(x0[j]);
#pragma unroll
  for (int j = 0; j < 4; j++) o[4 + j] = (short)f2bf(x1[j]);
  *(bf16x8_t*)(a.dst[which] + i) = o;
}

// C[m][n] = sum_k A[m][k] * Bt[n][k] + bias[n].  M,N,K multiples of 128/128/32.
// 256 threads = 4 waves in 2x2; wave tile 64x64 = 4x4 frags of 16x16; BK=32.
// blockIdx.z selects one of up to 3 independent GEMMs (fused QKV launch).
// mode: 0 = bf16 row-major C, 1 = f32 row-major C,
//       2 = bf16 transposed VT[b][h][d][s] (M=b*2048+s, N=h*64+d) output.
struct GemmArgs {
  const unsigned short* A[3];
  const unsigned short* Bt[3];
  const float* bias[3];
  void* C[3];
  int mode[3];
};

__global__ __launch_bounds__(256) void gemm_bt(GemmArgs ga, int M, int N, int K)
{
  __shared__ unsigned short As[2][128 * 32];   // 2 x 8KB
  __shared__ unsigned short Bs[2][128 * 32];   // 2 x 8KB  (32KB total)
  const int z = blockIdx.z;
  const unsigned short* __restrict__ A  = ga.A[z];
  const unsigned short* __restrict__ Bt = ga.Bt[z];
  const float* __restrict__ bias = ga.bias[z];
  void* __restrict__ C = ga.C[z];
  const int mode = ga.mode[z];

  const int t = threadIdx.x;
  const int l = t & 63;
  const int w = t >> 6;
  const int quad = l >> 4, n16 = l & 15;
  const int wm = (w & 1) * 64, wn = (w >> 1) * 64;
  const long m0 = (long)blockIdx.x * 128, n0 = (long)blockIdx.y * 128;

  f32x4_t acc[4][4] = {};

  // staging: thread t covers tile row t>>2 (+64 second half), cols (t&3)*8..+7
  // LDS dest t*16B == wave-uniform base + lane*16 (global_load_lds contract).
  const unsigned short* gA = A + (m0 + (t >> 2)) * (long)K + (t & 3) * 8;
  const unsigned short* gB = Bt + (n0 + (t >> 2)) * (long)K + (t & 3) * 8;
  const long rowskip = 64l * K;

  auto stage = [&](int buf, int kt) {
    GLDS16(gA + kt, &As[buf][t * 8]);
    GLDS16(gA + kt + rowskip, &As[buf][2048 + t * 8]);
    GLDS16(gB + kt, &Bs[buf][t * 8]);
    GLDS16(gB + kt + rowskip, &Bs[buf][2048 + t * 8]);
  };

  stage(0, 0);
  __syncthreads();                         // vmcnt(0) drain: buf0 visible

  int cur = 0;
  for (int kt = 0; kt < K; kt += 32, cur ^= 1) {
    if (kt + 32 < K) stage(cur ^ 1, kt + 32);   // issue FIRST: covered by MFMA below

    bf16x8_t af[4], bfr[4];
#pragma unroll
    for (int i = 0; i < 4; i++) {
      af[i]  = *(const bf16x8_t*)&As[cur][(wm + i * 16 + n16) * 32 + quad * 8];
      bfr[i] = *(const bf16x8_t*)&Bs[cur][(wn + i * 16 + n16) * 32 + quad * 8];
    }
#pragma unroll
    for (int mi = 0; mi < 4; mi++)
#pragma unroll
      for (int ni = 0; ni < 4; ni++)
        acc[mi][ni] = __builtin_amdgcn_mfma_f32_16x16x32_bf16(af[mi], bfr[ni], acc[mi][ni], 0, 0, 0);

    __syncthreads();   // drains vmcnt (next-buf staged) + lgkm (cur reads retired)
  }

  if (mode == 2) {
    // Transposed epilogue: write VT[b][h][d][s], b=m>>11, s=m&2047,
    // h=n>>6, d=n&63. r=0..3 are 4 consecutive s -> one 8B packed store.
    // A 128-row m-tile never straddles a 2048 boundary (2048 % 128 == 0).
#pragma unroll
    for (int ni = 0; ni < 4; ni++) {
      const long n = n0 + wn + ni * 16 + n16;
      const float bv = bias[n];
      const int h = (int)(n >> 6), d = (int)(n & 63);
#pragma unroll
      for (int mi = 0; mi < 4; mi++) {
        const long m = m0 + wm + mi * 16 + quad * 4;   // base of 4 consecutive rows
        const int bb = (int)(m >> 11), s = (int)(m & 2047);
        bf16x4_t o4;
#pragma unroll
        for (int r = 0; r < 4; r++) o4[r] = (short)f2bf(acc[mi][ni][r] + bv);
        *(bf16x4_t*)&((unsigned short*)C)[((size_t)(bb * 16 + h) * 64 + d) * 2048 + s] = o4;
      }
    }
  } else {
#pragma unroll
    for (int ni = 0; ni < 4; ni++) {
      const long n = n0 + wn + ni * 16 + n16;
      const float bv = bias[n];
#pragma unroll
      for (int mi = 0; mi < 4; mi++) {
#pragma unroll
        for (int r = 0; r < 4; r++) {
          const long m = m0 + wm + mi * 16 + quad * 4 + r;  // D: row=(l>>4)*4+reg, col=l&15
          const float v = acc[mi][ni][r] + bv;
          if (mode == 1) ((float*)C)[m * N + n] = v;
          else ((unsigned short*)C)[m * N + n] = f2bf(v);
        }
      }
    }
  }
}

// Fused attention (v9 verbatim -- the 241us floor of this decomposition).
// Grid 256 (1-D, XCD-decoded). 1024 threads = 16 waves, wave g: head g.
// Lane-local logits row (h=n16, q=g) via swapped mix-MFMA; p = 2^{S'}
// directly (no max; bounded logits, exact by shift-invariance).
// Double-buffered sraw/pbuf, ONE __syncthreads per k-tile:
//   iter i: PV(i-1)[pbuf parity i-1] || mix/exp/pack(i)[sraw parity i ->
//   pbuf parity i] || QK(i+1)[sraw parity i+1] -> __syncthreads.
__global__ __launch_bounds__(1024, 4) void attention_fused(
    const unsigned short* __restrict__ Qb, const unsigned short* __restrict__ Kb,
    const unsigned short* __restrict__ VT, const float* __restrict__ Wc,
    unsigned short* __restrict__ Obuf)
{
  __shared__ unsigned short sraw[2][512 * 36];  // [col=q*32+k][slot 0..31(+4)] 2x36864 B
  __shared__ unsigned short pbuf[2][16 * 580];  // [h]{q*36 + k}                2x18560 B
  __shared__ float lbuf[16 * 17];               // [h][q] stride 17             1088 B
  __shared__ unsigned short mmat[256];          // M~[g_out][h] row-major       512 B

  const int t = threadIdx.x;
  const int g = t >> 6, l = t & 63;
  const int quad = l >> 4, n16 = l & 15;

  // XCD decode: id&7 = XCD; batch pinned to an XCD half
  const int id = blockIdx.x;
  const int xcd = id & 7;
  const int b = xcd >> 2;
  const int qb = (xcd & 3) * 32 + (id >> 3);
  const int q0 = qb * 16;

  // zero both sraw buffers once: mix A-operand reads the never-written slot
  // half (h>=16 region after XOR) which must be 0, not garbage.
  for (int i = t; i < 2 * 512 * 36; i += 1024) (&sraw[0][0])[i] = 0;
  if (t < 256) {
    // M~ = (I + Wc) * (log2e / 8): exp2-domain logits
    const float v = ((((t >> 4) == (t & 15)) ? 1.0f : 0.0f) + Wc[t]) * 0.1803368801111204f;
    mmat[t] = f2bf(v);
  }
  __syncthreads();

  // mix B-frag: B[k=h=quad*8+j][n=g_out=n16]; zero for h>=16
  bf16x8_t mfrag;
  if (quad < 2) mfrag = *(const bf16x8_t*)&mmat[n16 * 16 + quad * 8];
  else { bf16x8_t z = {0, 0, 0, 0, 0, 0, 0, 0}; mfrag = z; }
  const int c7 = g >> 2;                     // col>>7 for this wave's mix chunks

  // Q A-frags: A[m=q=n16][k=d]
  bf16x8_t qf[2];
#pragma unroll
  for (int dr = 0; dr < 2; dr++)
    qf[dr] = *(const bf16x8_t*)&Qb[(size_t)(b * 2048 + q0 + n16) * 1024 + g * 64 + dr * 32 + quad * 8];

  const int slot = g ^ (quad << 3);          // sraw h-slot (writer quad == col>>7)
  const unsigned short* kptr = Kb + (size_t)(b * 2048 + n16) * 1024 + g * 64 + quad * 8;
  const unsigned short* vptr = VT + ((size_t)(b * 16 + g) * 64 + n16) * 2048 + quad * 8;

  bf16x8_t kf[2][2], vf[4];
  auto load_kf = [&](int kt) {
#pragma unroll
    for (int kc = 0; kc < 2; kc++)
#pragma unroll
      for (int dr = 0; dr < 2; dr++)
        kf[kc][dr] = *(const bf16x8_t*)(kptr + (size_t)(kt + kc * 16) * 1024 + dr * 32);
  };
  auto load_vf = [&](int kt) {
#pragma unroll
    for (int dc = 0; dc < 4; dc++)
      vf[dc] = *(const bf16x8_t*)(vptr + (size_t)dc * 16 * 2048 + kt);
  };
  auto qk_stage = [&](unsigned short* dst) {
    f32x4_t sf[2] = {};
#pragma unroll
    for (int kc = 0; kc < 2; kc++)
#pragma unroll
      for (int dr = 0; dr < 2; dr++)
        sf[kc] = __builtin_amdgcn_mfma_f32_16x16x32_bf16(qf[dr], kf[kc][dr], sf[kc], 0, 0, 0);
    // D: row=q=quad*4+r, col=key=kc*16+n16 -> dst[col=q*32+k][slot]
#pragma unroll
    for (int kc = 0; kc < 2; kc++)
#pragma unroll
      for (int r = 0; r < 4; r++)
        dst[((quad * 4 + r) * 32 + kc * 16 + n16) * 36 + slot] = f2bf(sf[kc][r]);
  };

  // prologue: QK(0) -> sraw[0]; prefetch K(1)
  load_kf(0);
  qk_stage(&sraw[0][0]);
  load_kf(32);
  __syncthreads();                            // sraw[0] visible

  f32x4_t o[4] = {};
  float l_run = 0.0f;

  for (int it = 0; it < 64; ++it) {
    const int cur = it & 1;
    const int oth = cur ^ 1;                  // parity of both (it-1) and (it+1)

    // ---- PV(it-1): accumulate (reads pbuf parity oth; no rescale) ----
    if (it > 0) {
      const unsigned short* pp = &pbuf[oth][g * 580 + n16 * 36 + quad * 8];
      bf16x4_t plo = *(const bf16x4_t*)pp;
      bf16x4_t phi = *(const bf16x4_t*)(pp + 4);
      bf16x8_t pf = {plo[0], plo[1], plo[2], plo[3], phi[0], phi[1], phi[2], phi[3]};
#pragma unroll
      for (int dc = 0; dc < 4; dc++)
        o[dc] = __builtin_amdgcn_mfma_f32_16x16x32_bf16(pf, vf[dc], o[dc], 0, 0, 0);
    }
    // ---- issue V(it) global loads (consumed by PV(it) next interval) ----
    load_vf(it * 32);

    // ---- head mix (swapped): D[key][g_out] from sraw[cur] ----
    f32x4_t mixd[2];
#pragma unroll
    for (int c2 = 0; c2 < 2; c2++) {
      const int c = g * 2 + c2;               // cols [32g+16c2, +16): q=g
      const unsigned short* sp = &sraw[cur][(c * 16 + n16) * 36 + ((quad ^ c7) << 3)];
      bf16x4_t lo = *(const bf16x4_t*)sp;     // A[m=key=n16][k=h=quad*8+j]
      bf16x4_t hi = *(const bf16x4_t*)(sp + 4);
      bf16x8_t aa = {lo[0], lo[1], lo[2], lo[3], hi[0], hi[1], hi[2], hi[3]};
      f32x4_t z = {};
      mixd[c2] = __builtin_amdgcn_mfma_f32_16x16x32_bf16(aa, mfrag, z, 0, 0, 0);
    }
    // lane holds S'[h=n16][q=g][key = c2*16 + quad*4 + r] (log2 domain)

    // ---- p = 2^{S'} directly (bounded logits; no max subtraction) ----
    float p[2][4];
    float lsum = 0.0f;
#pragma unroll
    for (int c2 = 0; c2 < 2; c2++)
#pragma unroll
      for (int r = 0; r < 4; r++) {
        p[c2][r] = exp2f(mixd[c2][r]);
        lsum += p[c2][r];
      }
    l_run += lsum;                            // lane-partial l; reduced at end

    // ---- pack P pairs in-register, write pbuf[cur] ----
    const int pbase = n16 * 580 + g * 36 + quad * 4;
#pragma unroll
    for (int c2 = 0; c2 < 2; c2++)
#pragma unroll
      for (int rp = 0; rp < 2; rp++) {
        unsigned pk;
        asm("v_cvt_pk_bf16_f32 %0, %1, %2"
            : "=v"(pk) : "v"(p[c2][2 * rp]), "v"(p[c2][2 * rp + 1]));
        *(unsigned*)&pbuf[cur][pbase + c2 * 16 + 2 * rp] = pk;
      }

    // ---- QK(it+1) -> sraw[oth]; prefetch K(it+2) ----
    if (it < 63) qk_stage(&sraw[oth][0]);
    if (it < 62) load_kf((it + 2) * 32);

    __syncthreads();  // publishes pbuf[cur], sraw[oth]; retires all LDS reads
  }

  // ---- epilogue: PV(63) (parity 1), l-reduce, normalize, store ----
  {
    const unsigned short* pp = &pbuf[1][g * 580 + n16 * 36 + quad * 8];
    bf16x4_t plo = *(const bf16x4_t*)pp;
    bf16x4_t phi = *(const bf16x4_t*)(pp + 4);
    bf16x8_t pf = {plo[0], plo[1], plo[2], plo[3], phi[0], phi[1], phi[2], phi[3]};
#pragma unroll
    for (int dc = 0; dc < 4; dc++)
      o[dc] = __builtin_amdgcn_mfma_f32_16x16x32_bf16(pf, vf[dc], o[dc], 0, 0, 0);
  }

  l_run += __shfl_xor(l_run, 16);
  l_run += __shfl_xor(l_run, 32);
  if (quad == 0) lbuf[n16 * 17 + g] = l_run;   // l for row (h=n16, q=g)
  __syncthreads();
  float linv[4];
#pragma unroll
  for (int r = 0; r < 4; r++) linv[r] = 1.0f / lbuf[g * 17 + quad * 4 + r];
#pragma unroll
  for (int dc = 0; dc < 4; dc++)
#pragma unroll
    for (int r = 0; r < 4; r++) {
      const float v = o[dc][r] * linv[r];
      Obuf[(size_t)(b * 2048 + q0 + quad * 4 + r) * 1024 + g * 64 + dc * 16 + n16] = f2bf(v);
    }
}

extern "C" void kernel_launch(void* const* d_in, const int* in_sizes, int n_in,
                              void* d_out, int out_size, void* d_ws, size_t ws_size,
                              hipStream_t stream) {
  const float* query = (const float*)d_in[0];
  const float* key   = (const float*)d_in[1];
  const float* value = (const float*)d_in[2];
  const float* Wq = (const float*)d_in[3];
  const float* bq = (const float*)d_in[4];
  const float* Wk = (const float*)d_in[5];
  const float* bk = (const float*)d_in[6];
  const float* Wv = (const float*)d_in[7];
  const float* bv = (const float*)d_in[8];
  const float* Wc = (const float*)d_in[9];
  // d_in[10] = bc: constant along softmax axis -> provably no effect on output
  const float* Wo = (const float*)d_in[11];
  const float* bo = (const float*)d_in[12];

  char* ws = (char*)d_ws;
  const size_t MB = 1024 * 1024;
  unsigned short* q_bf  = (unsigned short*)(ws);            // 8MB; later reused as Obuf
  unsigned short* k_bf  = (unsigned short*)(ws + 8 * MB);   // 8MB
  unsigned short* v_bf  = (unsigned short*)(ws + 16 * MB);  // 8MB
  unsigned short* wq_bf = (unsigned short*)(ws + 24 * MB);  // 2MB
  unsigned short* wk_bf = (unsigned short*)(ws + 26 * MB);  // 2MB
  unsigned short* wv_bf = (unsigned short*)(ws + 28 * MB);  // 2MB
  unsigned short* wo_bf = (unsigned short*)(ws + 30 * MB);  // 2MB
  unsigned short* Qb    = (unsigned short*)(ws + 32 * MB);  // 8MB
  unsigned short* Kb    = (unsigned short*)(ws + 40 * MB);  // 8MB
  unsigned short* VT    = (unsigned short*)(ws + 48 * MB);  // 8MB (V-proj writes VT directly)
  unsigned short* Obuf = q_bf;   // q_bf dead after Q-projection

  ConvArgs ca;
  ca.src[0] = query; ca.dst[0] = q_bf;  ca.n[0] = 2 * 2048 * 1024;
  ca.src[1] = key;   ca.dst[1] = k_bf;  ca.n[1] = 2 * 2048 * 1024;
  ca.src[2] = value; ca.dst[2] = v_bf;  ca.n[2] = 2 * 2048 * 1024;
  ca.src[3] = Wq;    ca.dst[3] = wq_bf; ca.n[3] = 1024 * 1024;
  ca.src[4] = Wk;    ca.dst[4] = wk_bf; ca.n[4] = 1024 * 1024;
  ca.src[5] = Wv;    ca.dst[5] = wv_bf; ca.n[5] = 1024 * 1024;
  ca.src[6] = Wo;    ca.dst[6] = wo_bf; ca.n[6] = 1024 * 1024;
  convert_f32_bf16<<<dim3(2048, 7), 256, 0, stream>>>(ca);

  GemmArgs g3;
  g3.A[0] = q_bf; g3.Bt[0] = wq_bf; g3.bias[0] = bq; g3.C[0] = Qb; g3.mode[0] = 0;
  g3.A[1] = k_bf; g3.Bt[1] = wk_bf; g3.bias[1] = bk; g3.C[1] = Kb; g3.mode[1] = 0;
  g3.A[2] = v_bf; g3.Bt[2] = wv_bf; g3.bias[2] = bv; g3.C[2] = VT; g3.mode[2] = 2;
  gemm_bt<<<dim3(32, 8, 3), 256, 0, stream>>>(g3, 4096, 1024, 1024);

  attention_fused<<<dim3(256), 1024, 0, stream>>>(Qb, Kb, VT, Wc, Obuf);

  GemmArgs g1;
  g1.A[0] = Obuf; g1.Bt[0] = wo_bf; g1.bias[0] = bo; g1.C[0] = d_out; g1.mode[0] = 1;
  g1.A[1] = g1.A[0]; g1.Bt[1] = g1.Bt[0]; g1.bias[1] = g1.bias[0]; g1.C[1] = g1.C[0]; g1.mode[1] = 1;
  g1.A[2] = g1.A[0]; g1.Bt[2] = g1.Bt[0]; g1.bias[2] = g1.bias[0]; g1.C[2] = g1.C[0]; g1.mode[2] = 1;
  gemm_bt<<<dim3(32, 8, 1), 256, 0, stream>>>(g1, 4096, 1024, 1024);
}